// Round 1
// baseline (53760.779 us; speedup 1.0000x reference)
//
#include <hip/hip_runtime.h>

#define S_LEN   4096
#define R_DIM   512
#define N_BATCH 32
#define D_IN_   8
#define BLK     24
#define PSTR    516              // partial ring stride (pad 512 -> 516 to spread banks)
#define CAP     26880            // tap-1 sparse entry capacity (mean 26214, +4.3 sigma)
#define LEAK_   0.1f

#define LDS_POOL_OFF   0
#define LDS_CPTR_OFF   (CAP * 4)                       // 107520
#define LDS_PART_OFF   (LDS_CPTR_OFF + 2052)           // 109572
#define LDS_HA_OFF     (LDS_PART_OFF + BLK * PSTR * 4) // 159108
#define LDS_HB_OFF     (LDS_HA_OFF + R_DIM * 4)        // 161156
#define LDS_BYTES      (LDS_HB_OFF + R_DIM * 4)        // 163204 <= 163840

typedef __attribute__((ext_vector_type(8))) short bf16x8;
typedef __attribute__((ext_vector_type(4))) float f32x4;

__device__ __forceinline__ unsigned f2bf(float f) {
  unsigned u = __float_as_uint(f);
  return (u + 0x7FFFu + ((u >> 16) & 1u)) >> 16;   // RNE bf16 (NaN irrelevant here)
}

// B fragment: B[k][col] for k = k0 + kb*8 + i, i=0..7 (16x16x32 bf16 layout)
__device__ __forceinline__ bf16x8 load_bfrag(const float* __restrict__ W,
                                             const unsigned short* __restrict__ Wc,
                                             int use_cache, int k0, int col, int kb) {
  bf16x8 b;
  if (use_cache) {
    // Wc is per-tap base, layout [col][r] (transposed, bf16) -> one 16B load
    const unsigned short* p = Wc + (size_t)col * R_DIM + k0 + kb * 8;
    b = *(const bf16x8*)p;
  } else {
    const float* p = W + (size_t)(k0 + kb * 8) * R_DIM + col;
#pragma unroll
    for (int i = 0; i < 8; ++i) b[i] = (short)f2bf(p[(size_t)i * R_DIM]);
  }
  return b;
}

// A fragment: A[row][k] for k = k0 + kb*8 + i (history row hbase), zeros if !valid
__device__ __forceinline__ bf16x8 load_afrag(const float* __restrict__ hbase,
                                             bool valid, int k0, int kb) {
  bf16x8 a;
  if (valid) {
    const float4* p = (const float4*)(hbase + k0 + kb * 8);
    float4 v0 = p[0], v1 = p[1];
    a[0] = (short)f2bf(v0.x); a[1] = (short)f2bf(v0.y);
    a[2] = (short)f2bf(v0.z); a[3] = (short)f2bf(v0.w);
    a[4] = (short)f2bf(v1.x); a[5] = (short)f2bf(v1.y);
    a[6] = (short)f2bf(v1.z); a[7] = (short)f2bf(v1.w);
  } else {
#pragma unroll
    for (int i = 0; i < 8; ++i) a[i] = 0;
  }
  return a;
}

// prep: Wc[tap][j][r] = bf16(Wfb[tap][r][j])
extern "C" __global__ void prep_wc(const float* __restrict__ Wfb,
                                   unsigned short* __restrict__ Wc) {
  int blk = blockIdx.x;            // tap*512 + j
  int r   = threadIdx.x;
  int tap = blk >> 9, jc = blk & 511;
  float w = Wfb[((size_t)tap * R_DIM + r) * R_DIM + jc];
  Wc[((size_t)tap * R_DIM + jc) * R_DIM + r] = (unsigned short)f2bf(w);
}

extern "C" __global__ void __launch_bounds__(1024, 1)
reservoir_kernel(const float* __restrict__ x, const float* __restrict__ Win,
                 const float* __restrict__ Wfb, const float* __restrict__ bias,
                 float* __restrict__ out, const unsigned short* __restrict__ Wc,
                 int use_cache) {
  extern __shared__ char lds[];
  unsigned* pool   = (unsigned*)(lds + LDS_POOL_OFF);
  unsigned* colptr = (unsigned*)(lds + LDS_CPTR_OFF);
  float*    partial= (float*)(lds + LDS_PART_OFF);
  float*    hA     = (float*)(lds + LDS_HA_OFF);
  float*    hB     = (float*)(lds + LDS_HB_OFF);

  const int b = blockIdx.x, tid = threadIdx.x;
  const int lane = tid & 63, wv = tid >> 6;
  float* outB = out + (size_t)b * S_LEN * R_DIM;

  // cross-replay L1 staleness guard (harness replays without repoisoning d_out)
  __builtin_amdgcn_fence(__ATOMIC_ACQUIRE, "agent");

  // ---- build tap-1 (delay 1 = Wfb[0]) sparse CSC in LDS ----
  if (tid < R_DIM) {
    int c = 0;
    for (int r = 0; r < R_DIM; ++r)
      c += (Wfb[(size_t)r * R_DIM + tid] != 0.0f) ? 1 : 0;
    colptr[tid + 1] = (unsigned)c;
  }
  if (tid == 1023) colptr[0] = 0;
  __syncthreads();
  if (tid == 0) {
    unsigned run = 0;
    for (int i = 1; i <= R_DIM; ++i) { run += colptr[i]; colptr[i] = run; }
  }
  __syncthreads();
  if (tid < R_DIM) {
    unsigned p = colptr[tid];
    for (int r = 0; r < R_DIM; ++r) {
      float w = Wfb[(size_t)r * R_DIM + tid];
      if (w != 0.0f) {
        if (p < CAP) pool[p] = (f2bf(w) << 16) | (unsigned)r;
        ++p;
      }
    }
  }
  for (int i = tid; i < BLK * PSTR; i += 1024) partial[i] = 0.f;
  if (tid < R_DIM) { hA[tid] = 0.f; hB[tid] = 0.f; }
  __syncthreads();

  // persistent per-thread state
  const int j = tid >> 1, half = tid & 1;
  float win_[D_IN_];
#pragma unroll
  for (int i = 0; i < D_IN_; ++i) win_[i] = Win[(size_t)j * D_IN_ + i];
  const float bj = bias[j];
  unsigned e0 = colptr[j], e1 = colptr[j + 1];
  unsigned mid = e0 + ((e1 - e0 + 1u) >> 1);
  unsigned gs = half ? mid : e0;
  unsigned ge = half ? e1 : mid;

  const int row16 = lane & 15, kb = lane >> 4;
  const int j0 = wv * 32;    // 16 waves x 32 output cols

  float* hprev = hA;
  float* hnext = hB;
  int tm = 0;                // t % BLK

#pragma unroll 1
  for (int t = 0; t < S_LEN; ++t) {
    // ================= Phase A (every step, serial part) =================
    float fb = 0.f;
    for (unsigned e = gs; e < ge; ++e) {
      unsigned w = pool[e];
      fb += __uint_as_float(w & 0xFFFF0000u) * hprev[w & 511u];
    }
    fb += __shfl_xor(fb, 1, 64);
    if (half == 0) {
      const float* xp = x + ((size_t)b * S_LEN + t) * D_IN_;
      float d = 0.f;
#pragma unroll
      for (int i = 0; i < D_IN_; ++i) d += win_[i] * xp[i];
      float a  = fb + partial[tm * PSTR + j] + d + bj;
      float z  = tanhf(a);
      float hn = (1.0f - LEAK_) * hprev[j] + LEAK_ * z;
      hnext[j] = hn;
      outB[(size_t)t * R_DIM + j] = hn;   // d_out doubles as the history buffer
    }
    __syncthreads();

    const int tn = t + 1;
    if ((tn & 3) == 0 && tn < S_LEN) {
      // ========== B24: taps {24,96,168} for steps tn..tn+23 (overwrite) ==========
      if (tm == BLK - 1) {
        const int s0 = tn;
        f32x4 acc[2][2];
#pragma unroll
        for (int mt = 0; mt < 2; ++mt)
#pragma unroll
          for (int nt = 0; nt < 2; ++nt)
            acc[mt][nt] = (f32x4){0.f, 0.f, 0.f, 0.f};
        const int taud[3] = {24, 96, 168};
#pragma unroll 1
        for (int ti = 0; ti < 3; ++ti) {
          const int tau = taud[ti];
          const float* W           = Wfb + (size_t)(ti + 2) * R_DIM * R_DIM;
          const unsigned short* Wt = Wc  + (size_t)(ti + 2) * R_DIM * R_DIM;
#pragma unroll 1
          for (int k0 = 0; k0 < R_DIM; k0 += 32) {
            bf16x8 afr[2], bfr[2];
#pragma unroll
            for (int mt = 0; mt < 2; ++mt) {
              int srow = mt * 16 + row16;
              int hs = s0 + srow - tau;
              bool v = (srow < BLK) && (hs >= 0);   // never reads future rows
              afr[mt] = load_afrag(outB + (size_t)(v ? hs : 0) * R_DIM, v, k0, kb);
            }
#pragma unroll
            for (int nt = 0; nt < 2; ++nt)
              bfr[nt] = load_bfrag(W, Wt, use_cache, k0, j0 + nt * 16 + row16, kb);
#pragma unroll
            for (int mt = 0; mt < 2; ++mt)
#pragma unroll
              for (int nt = 0; nt < 2; ++nt)
                acc[mt][nt] = __builtin_amdgcn_mfma_f32_16x16x32_bf16(
                    afr[mt], bfr[nt], acc[mt][nt], 0, 0, 0);
          }
        }
        // C layout: col = lane&15, row = (lane>>4)*4 + q
#pragma unroll
        for (int mt = 0; mt < 2; ++mt)
#pragma unroll
          for (int q = 0; q < 4; ++q) {
            int srow = mt * 16 + kb * 4 + q;
            if (srow < BLK) {
#pragma unroll
              for (int nt = 0; nt < 2; ++nt)
                partial[srow * PSTR + j0 + nt * 16 + row16] = acc[mt][nt][q];
            }
          }
        __syncthreads();
      }
      // ========== B4: tap {4} for steps tn..tn+3 (accumulate) ==========
      {
        const int s0 = tn;
        const int sb = (tm == BLK - 1) ? 0 : tm + 1;   // s0 % 24
        const float* W           = Wfb + (size_t)1 * R_DIM * R_DIM;
        const unsigned short* Wt = Wc  + (size_t)1 * R_DIM * R_DIM;
        f32x4 acc[2];
        acc[0] = (f32x4){0.f, 0.f, 0.f, 0.f};
        acc[1] = (f32x4){0.f, 0.f, 0.f, 0.f};
#pragma unroll 1
        for (int k0 = 0; k0 < R_DIM; k0 += 32) {
          int srow = row16;
          int hs = s0 + srow - 4;                      // s0 >= 4 always
          bool v = (srow < 4);
          bf16x8 af = load_afrag(outB + (size_t)(v ? hs : 0) * R_DIM, v, k0, kb);
#pragma unroll
          for (int nt = 0; nt < 2; ++nt) {
            bf16x8 bf_ = load_bfrag(W, Wt, use_cache, k0, j0 + nt * 16 + row16, kb);
            acc[nt] = __builtin_amdgcn_mfma_f32_16x16x32_bf16(af, bf_, acc[nt], 0, 0, 0);
          }
        }
#pragma unroll
        for (int q = 0; q < 4; ++q) {
          int srow = kb * 4 + q;
          if (srow < 4) {
#pragma unroll
            for (int nt = 0; nt < 2; ++nt)
              partial[(sb + srow) * PSTR + j0 + nt * 16 + row16] += acc[nt][q];
          }
        }
        __syncthreads();
      }
    }
    float* tsw = hprev; hprev = hnext; hnext = tsw;
    tm = (tm == BLK - 1) ? 0 : tm + 1;
  }
}

extern "C" void kernel_launch(void* const* d_in, const int* in_sizes, int n_in,
                              void* d_out, int out_size, void* d_ws, size_t ws_size,
                              hipStream_t stream) {
  const float* x    = (const float*)d_in[0];
  const float* Win  = (const float*)d_in[1];
  const float* Wfb  = (const float*)d_in[2];
  const float* bias = (const float*)d_in[3];
  float* out = (float*)d_out;

  const size_t wc_bytes = (size_t)5 * R_DIM * R_DIM * sizeof(unsigned short); // 2.62 MB
  int use_cache = (d_ws != nullptr && ws_size >= wc_bytes) ? 1 : 0;
  unsigned short* Wc = use_cache ? (unsigned short*)d_ws : (unsigned short*)Wfb;

  if (use_cache) {
    hipLaunchKernelGGL(prep_wc, dim3(5 * R_DIM), dim3(R_DIM), 0, stream, Wfb, Wc);
  }
  hipFuncSetAttribute((const void*)reservoir_kernel,
                      hipFuncAttributeMaxDynamicSharedMemorySize, LDS_BYTES);
  hipLaunchKernelGGL(reservoir_kernel, dim3(N_BATCH), dim3(1024), LDS_BYTES, stream,
                     x, Win, Wfb, bias, out, (const unsigned short*)Wc, use_cache);
}

// Round 2
// 40932.394 us; speedup vs baseline: 1.3134x; 1.3134x over previous
//
#include <hip/hip_runtime.h>

#define S_LEN   4096
#define R_DIM   512
#define N_BATCH 32
#define D_IN_   8
#define BLK     24
#define PSTR    516
#define LEAK_   0.1f
#define MAXS    64
#define NTHR    1024
#define RSTR    520              // ring stride in shorts (1040 B, 16B aligned, breaks bank wrap)

// ---------------- fast-path LDS layout ----------------
#define F_RING_OFF   0
#define F_RING_SH    (32 * RSTR)                        // 16640 shorts
#define F_PART_OFF   (F_RING_SH * 2)                    // 33280
#define F_HA_OFF     (F_PART_OFF + BLK * PSTR * 4)      // 82816 (128B aligned)
#define F_HB_OFF     (F_HA_OFF + R_DIM * 4)             // 84864 (128B aligned)
#define F_LDS_BYTES  (F_HB_OFF + R_DIM * 4)             // 86912

// ---------------- workspace layout (bytes) ----------------
#define WS_WC        0
#define WS_WC_SZ     (5 * R_DIM * R_DIM * 2)            // 2,621,440
#define WS_POOL      (WS_WC + WS_WC_SZ)
#define WS_POOL_SZ   (MAXS * NTHR * 4)                  // 262,144
#define WS_WNS       (WS_POOL + WS_POOL_SZ)
#define WS_WNS_SZ    64
#define WS_LISTS     (WS_WNS + WS_WNS_SZ)
#define WS_LISTS_SZ  (NTHR * MAXS * 4)                  // 262,144
#define WS_CNT       (WS_LISTS + WS_LISTS_SZ)
#define WS_CNT_SZ    (NTHR * 4)
#define WS_TOTAL     (WS_CNT + WS_CNT_SZ)               // 3,149,952

// ---------------- fallback (round-1) LDS layout ----------------
#define CAP            26880
#define LDS_POOL_OFF   0
#define LDS_CPTR_OFF   (CAP * 4)
#define LDS_PART_OFF   (LDS_CPTR_OFF + 2052)
#define LDS_HA_OFF     (LDS_PART_OFF + BLK * PSTR * 4)
#define LDS_HB_OFF     (LDS_HA_OFF + R_DIM * 4)
#define LDS_BYTES_FB   (LDS_HB_OFF + R_DIM * 4)

typedef __attribute__((ext_vector_type(8))) short bf16x8;
typedef __attribute__((ext_vector_type(4))) float f32x4;

__device__ __forceinline__ unsigned f2bf(float f) {
  unsigned u = __float_as_uint(f);
  return (u + 0x7FFFu + ((u >> 16) & 1u)) >> 16;
}

__device__ __forceinline__ bf16x8 zero8() {
  bf16x8 a;
#pragma unroll
  for (int i = 0; i < 8; ++i) a[i] = 0;
  return a;
}

// A fragment from f32 global history (taps 96/168)
__device__ __forceinline__ bf16x8 load_afrag_g(const float* __restrict__ hbase,
                                               bool valid, int k0, int kb) {
  if (!valid) return zero8();
  const float4* p = (const float4*)(hbase + k0 + kb * 8);
  float4 v0 = p[0], v1 = p[1];
  bf16x8 a;
  a[0] = (short)f2bf(v0.x); a[1] = (short)f2bf(v0.y);
  a[2] = (short)f2bf(v0.z); a[3] = (short)f2bf(v0.w);
  a[4] = (short)f2bf(v1.x); a[5] = (short)f2bf(v1.y);
  a[6] = (short)f2bf(v1.z); a[7] = (short)f2bf(v1.w);
  return a;
}

// B fragment from bf16 Wc cache ([tap][col][r]) or f32 Wfb fallback
__device__ __forceinline__ bf16x8 load_bfrag(const float* __restrict__ W,
                                             const unsigned short* __restrict__ Wc,
                                             int use_cache, int k0, int col, int kb) {
  bf16x8 b;
  if (use_cache) {
    const unsigned short* p = Wc + (size_t)col * R_DIM + k0 + kb * 8;
    b = *(const bf16x8*)p;
  } else {
    const float* p = W + (size_t)(k0 + kb * 8) * R_DIM + col;
#pragma unroll
    for (int i = 0; i < 8; ++i) b[i] = (short)f2bf(p[(size_t)i * R_DIM]);
  }
  return b;
}

// ================= prep kernels =================
extern "C" __global__ void prep_wc(const float* __restrict__ Wfb,
                                   unsigned short* __restrict__ Wc) {
  int blk = blockIdx.x, r = threadIdx.x;
  int tap = blk >> 9, jc = blk & 511;
  float w = Wfb[((size_t)tap * R_DIM + r) * R_DIM + jc];
  Wc[((size_t)tap * R_DIM + jc) * R_DIM + r] = (unsigned short)f2bf(w);
}

// per-thread compact nonzero list of W_fb[0] column (parity-split across the pair)
extern "C" __global__ void prep_lists(const float* __restrict__ Wfb,
                                      unsigned* __restrict__ lists,
                                      unsigned* __restrict__ cnt) {
  int tid = threadIdx.x, j = tid >> 1, half = tid & 1;
  unsigned c = 0; int par = 0;
  for (int r = 0; r < R_DIM; ++r) {
    float w = Wfb[(size_t)r * R_DIM + j];
    if (w != 0.0f) {
      if ((par & 1) == half && c < MAXS)
        lists[(size_t)tid * MAXS + c++] = (f2bf(w) << 16) | (unsigned)(r * 4);
      ++par;
    }
  }
  cnt[tid] = c;
}

// greedy bank-conflict-free slot scheduler, one thread per wave
extern "C" __global__ void prep_sched(const unsigned* __restrict__ lists,
                                      const unsigned* __restrict__ cnt,
                                      unsigned* __restrict__ pool,
                                      unsigned* __restrict__ wns) {
  __shared__ unsigned char L[16][MAXS][32];
  int w = threadIdx.x;
  if (w >= 16) return;
  for (int s = 0; s < MAXS; ++s)
    for (int b = 0; b < 32; ++b) L[w][s][b] = 0;
  // sentinel-init this wave's pool columns
  for (int s = 0; s < MAXS; ++s)
    for (int lane = 0; lane < 64; ++lane)
      pool[s * NTHR + w * 64 + lane] = 0xFFFFFFFFu;
  int maxs_used = 4;
  for (int lane = 0; lane < 64; ++lane) {
    int tid = w * 64 + lane;
    unsigned c = cnt[tid];
    unsigned long long used = 0ull;
    for (unsigned e = 0; e < c; ++e) {
      unsigned u = lists[(size_t)tid * MAXS + e];
      unsigned bank = (u >> 2) & 31u;
      int best = -1; unsigned bl = 255u;
      for (int s = (int)e; s < MAXS; ++s) {       // slots < e already used by this lane
        if ((used >> s) & 1ull) continue;
        unsigned ld = L[w][s][bank];
        if (ld < 2u) { best = s; break; }
        if (ld < bl) { bl = ld; best = s; }
      }
      if (best < 0) {                              // shouldn't happen; emergency scan
        for (int s = 0; s < MAXS; ++s) if (!((used >> s) & 1ull)) { best = s; break; }
      }
      pool[best * NTHR + tid] = u;
      used |= 1ull << best;
      L[w][best][bank]++;
      if (best + 1 > maxs_used) maxs_used = best + 1;
    }
  }
  int ns = (maxs_used + 3) & ~3;
  if (ns > MAXS) ns = MAXS;
  wns[w] = (unsigned)ns;
  // dummy-fill unassigned (s < ns) with zero-weight entries on low-load banks
  for (int lane = 0; lane < 64; ++lane) {
    int tid = w * 64 + lane;
    for (int s = 0; s < ns; ++s) {
      if (pool[s * NTHR + tid] != 0xFFFFFFFFu) continue;
      unsigned bestb = 0, bl = 255u;
#pragma unroll
      for (int k = 0; k < 4; ++k) {
        unsigned b = (unsigned)((s * 7 + lane * 3 + k * 11) & 31);
        unsigned ld = L[w][s][b];
        if (ld < bl) { bl = ld; bestb = b; }
      }
      pool[s * NTHR + tid] = bestb * 4u;           // weight bits = 0
      L[w][s][bestb]++;
    }
  }
}

// ================= fast main kernel =================
#define GSTEP(u, acc) \
  { acc += __uint_as_float((u) & 0xFFFF0000u) * \
           *(const float*)((const char*)hprev + ((u) & 2047u)); }

extern "C" __global__ void __launch_bounds__(1024, 1)
reservoir_fast(const float* __restrict__ x, const float* __restrict__ Win,
               const float* __restrict__ Wfb, const float* __restrict__ bias,
               float* __restrict__ out, const unsigned short* __restrict__ Wc,
               const unsigned* __restrict__ pool, const unsigned* __restrict__ wns) {
  extern __shared__ char lds[];
  unsigned short* ring = (unsigned short*)(lds + F_RING_OFF);
  float* partial = (float*)(lds + F_PART_OFF);
  float* hA = (float*)(lds + F_HA_OFF);
  float* hB = (float*)(lds + F_HB_OFF);

  const int b = blockIdx.x, tid = threadIdx.x;
  const int lane = tid & 63, wv = tid >> 6;
  float* outB = out + (size_t)b * S_LEN * R_DIM;

  __builtin_amdgcn_fence(__ATOMIC_ACQUIRE, "agent");

  for (int i = tid; i < F_RING_SH; i += NTHR) ring[i] = 0;
  for (int i = tid; i < BLK * PSTR; i += NTHR) partial[i] = 0.f;
  if (tid < R_DIM) { hA[tid] = 0.f; hB[tid] = 0.f; }
  __syncthreads();

  const int j = tid >> 1, half = tid & 1;
  float win_[D_IN_];
#pragma unroll
  for (int i = 0; i < D_IN_; ++i) win_[i] = Win[(size_t)j * D_IN_ + i];
  const float bj = bias[j];
  const unsigned ns = __builtin_amdgcn_readfirstlane(wns[wv]);
  const unsigned* poolT = pool + tid;

  const int row16 = lane & 15, kb = lane >> 4;
  const int j0 = wv * 32;

  float* hprev = hA;
  float* hnext = hB;
  int tm = 0;

#pragma unroll 1
  for (int t = 0; t < S_LEN; ++t) {
    // -------- Phase A: serial tap-1 sparse gather (bank-scheduled) --------
    const float4* xp = (const float4*)(x + ((size_t)b * S_LEN + t) * D_IN_);
    float4 xv0 = xp[0], xv1 = xp[1];

    float fb0 = 0.f, fb1 = 0.f;
    unsigned c0 = poolT[0], c1 = poolT[NTHR], c2 = poolT[2 * NTHR], c3 = poolT[3 * NTHR];
#pragma unroll 1
    for (unsigned s = 4; s < ns; s += 4) {
      unsigned n0 = poolT[(s + 0) * NTHR], n1 = poolT[(s + 1) * NTHR];
      unsigned n2 = poolT[(s + 2) * NTHR], n3 = poolT[(s + 3) * NTHR];
      GSTEP(c0, fb0); GSTEP(c1, fb1); GSTEP(c2, fb0); GSTEP(c3, fb1);
      c0 = n0; c1 = n1; c2 = n2; c3 = n3;
    }
    GSTEP(c0, fb0); GSTEP(c1, fb1); GSTEP(c2, fb0); GSTEP(c3, fb1);

    float fb = fb0 + fb1;
    fb += __shfl_xor(fb, 1, 64);
    if (half == 0) {
      float d = xv0.x * win_[0] + xv0.y * win_[1] + xv0.z * win_[2] + xv0.w * win_[3]
              + xv1.x * win_[4] + xv1.y * win_[5] + xv1.z * win_[6] + xv1.w * win_[7];
      float a  = fb + partial[tm * PSTR + j] + d + bj;
      float z  = tanhf(a);
      float hn = (1.0f - LEAK_) * hprev[j] + LEAK_ * z;
      hnext[j] = hn;
      ring[(t & 31) * RSTR + j] = (unsigned short)f2bf(hn);
      outB[(size_t)t * R_DIM + j] = hn;
    }
    __syncthreads();

    const int tn = t + 1;
    if ((tn & 3) == 0 && tn < S_LEN) {
      // ---- B24: taps {24,96,168} for steps tn..tn+23 (overwrite partial) ----
      if (tm == BLK - 1) {
        const int s0 = tn;
        f32x4 acc[2][2];
#pragma unroll
        for (int mt = 0; mt < 2; ++mt)
#pragma unroll
          for (int nt = 0; nt < 2; ++nt)
            acc[mt][nt] = (f32x4){0.f, 0.f, 0.f, 0.f};

        // tap 24: A from LDS bf16 ring
        {
          const unsigned short* Wt = Wc + (size_t)2 * R_DIM * R_DIM;
#pragma unroll 1
          for (int k0 = 0; k0 < R_DIM; k0 += 32) {
            bf16x8 afr[2], bfr[2];
#pragma unroll
            for (int mt = 0; mt < 2; ++mt) {
              int srow = mt * 16 + row16;
              if (srow < BLK) {
                int rr = (s0 + srow - 24) & 31;
                afr[mt] = *(const bf16x8*)(ring + rr * RSTR + k0 + kb * 8);
              } else afr[mt] = zero8();
            }
#pragma unroll
            for (int nt = 0; nt < 2; ++nt)
              bfr[nt] = load_bfrag(nullptr, Wt, 1, k0, j0 + nt * 16 + row16, kb);
#pragma unroll
            for (int mt = 0; mt < 2; ++mt)
#pragma unroll
              for (int nt = 0; nt < 2; ++nt)
                acc[mt][nt] = __builtin_amdgcn_mfma_f32_16x16x32_bf16(
                    afr[mt], bfr[nt], acc[mt][nt], 0, 0, 0);
          }
        }
        // taps 96, 168: A from global f32 history
        const int taud[2] = {96, 168};
#pragma unroll 1
        for (int ti = 0; ti < 2; ++ti) {
          const int tau = taud[ti];
          const unsigned short* Wt = Wc + (size_t)(ti + 3) * R_DIM * R_DIM;
#pragma unroll 1
          for (int k0 = 0; k0 < R_DIM; k0 += 32) {
            bf16x8 afr[2], bfr[2];
#pragma unroll
            for (int mt = 0; mt < 2; ++mt) {
              int srow = mt * 16 + row16;
              int hs = s0 + srow - tau;
              bool v = (srow < BLK) && (hs >= 0);
              afr[mt] = load_afrag_g(outB + (size_t)(v ? hs : 0) * R_DIM, v, k0, kb);
            }
#pragma unroll
            for (int nt = 0; nt < 2; ++nt)
              bfr[nt] = load_bfrag(nullptr, Wt, 1, k0, j0 + nt * 16 + row16, kb);
#pragma unroll
            for (int mt = 0; mt < 2; ++mt)
#pragma unroll
              for (int nt = 0; nt < 2; ++nt)
                acc[mt][nt] = __builtin_amdgcn_mfma_f32_16x16x32_bf16(
                    afr[mt], bfr[nt], acc[mt][nt], 0, 0, 0);
          }
        }
#pragma unroll
        for (int mt = 0; mt < 2; ++mt)
#pragma unroll
          for (int q = 0; q < 4; ++q) {
            int srow = mt * 16 + kb * 4 + q;
            if (srow < BLK) {
#pragma unroll
              for (int nt = 0; nt < 2; ++nt)
                partial[srow * PSTR + j0 + nt * 16 + row16] = acc[mt][nt][q];
            }
          }
        __syncthreads();
      }
      // ---- B4: tap {4} for steps tn..tn+3 (accumulate into partial) ----
      {
        const int s0 = tn;
        const int sb = (tm == BLK - 1) ? 0 : tm + 1;
        const unsigned short* Wt = Wc + (size_t)1 * R_DIM * R_DIM;
        f32x4 acc[2];
        acc[0] = (f32x4){0.f, 0.f, 0.f, 0.f};
        acc[1] = (f32x4){0.f, 0.f, 0.f, 0.f};
#pragma unroll 1
        for (int k0 = 0; k0 < R_DIM; k0 += 32) {
          bf16x8 af;
          int srow = row16;
          if (srow < 4) {
            int rr = (s0 + srow - 4) & 31;
            af = *(const bf16x8*)(ring + rr * RSTR + k0 + kb * 8);
          } else af = zero8();
#pragma unroll
          for (int nt = 0; nt < 2; ++nt) {
            bf16x8 bf_ = load_bfrag(nullptr, Wt, 1, k0, j0 + nt * 16 + row16, kb);
            acc[nt] = __builtin_amdgcn_mfma_f32_16x16x32_bf16(af, bf_, acc[nt], 0, 0, 0);
          }
        }
#pragma unroll
        for (int q = 0; q < 4; ++q) {
          int srow = kb * 4 + q;
          if (srow < 4) {
#pragma unroll
            for (int nt = 0; nt < 2; ++nt)
              partial[(sb + srow) * PSTR + j0 + nt * 16 + row16] += acc[nt][q];
          }
        }
        __syncthreads();
      }
    }
    float* tsw = hprev; hprev = hnext; hnext = tsw;
    tm = (tm == BLK - 1) ? 0 : tm + 1;
  }
}

// ================= fallback: round-1 kernel (correct, slow) =================
extern "C" __global__ void __launch_bounds__(1024, 1)
reservoir_fb(const float* __restrict__ x, const float* __restrict__ Win,
             const float* __restrict__ Wfb, const float* __restrict__ bias,
             float* __restrict__ out, const unsigned short* __restrict__ Wc,
             int use_cache) {
  extern __shared__ char lds[];
  unsigned* pool   = (unsigned*)(lds + LDS_POOL_OFF);
  unsigned* colptr = (unsigned*)(lds + LDS_CPTR_OFF);
  float*    partial= (float*)(lds + LDS_PART_OFF);
  float*    hA     = (float*)(lds + LDS_HA_OFF);
  float*    hB     = (float*)(lds + LDS_HB_OFF);
  const int b = blockIdx.x, tid = threadIdx.x;
  const int lane = tid & 63, wv = tid >> 6;
  float* outB = out + (size_t)b * S_LEN * R_DIM;
  __builtin_amdgcn_fence(__ATOMIC_ACQUIRE, "agent");
  if (tid < R_DIM) {
    int c = 0;
    for (int r = 0; r < R_DIM; ++r) c += (Wfb[(size_t)r * R_DIM + tid] != 0.0f) ? 1 : 0;
    colptr[tid + 1] = (unsigned)c;
  }
  if (tid == 1023) colptr[0] = 0;
  __syncthreads();
  if (tid == 0) { unsigned run = 0; for (int i = 1; i <= R_DIM; ++i) { run += colptr[i]; colptr[i] = run; } }
  __syncthreads();
  if (tid < R_DIM) {
    unsigned p = colptr[tid];
    for (int r = 0; r < R_DIM; ++r) {
      float w = Wfb[(size_t)r * R_DIM + tid];
      if (w != 0.0f) { if (p < CAP) pool[p] = (f2bf(w) << 16) | (unsigned)r; ++p; }
    }
  }
  for (int i = tid; i < BLK * PSTR; i += 1024) partial[i] = 0.f;
  if (tid < R_DIM) { hA[tid] = 0.f; hB[tid] = 0.f; }
  __syncthreads();
  const int j = tid >> 1, half = tid & 1;
  float win_[D_IN_];
#pragma unroll
  for (int i = 0; i < D_IN_; ++i) win_[i] = Win[(size_t)j * D_IN_ + i];
  const float bj = bias[j];
  unsigned e0 = colptr[j], e1 = colptr[j + 1];
  unsigned mid = e0 + ((e1 - e0 + 1u) >> 1);
  unsigned gs = half ? mid : e0, ge = half ? e1 : mid;
  const int row16 = lane & 15, kb = lane >> 4, j0 = wv * 32;
  float* hprev = hA; float* hnext = hB; int tm = 0;
#pragma unroll 1
  for (int t = 0; t < S_LEN; ++t) {
    float fb = 0.f;
    for (unsigned e = gs; e < ge; ++e) {
      unsigned w = pool[e];
      fb += __uint_as_float(w & 0xFFFF0000u) * hprev[w & 511u];
    }
    fb += __shfl_xor(fb, 1, 64);
    if (half == 0) {
      const float* xp = x + ((size_t)b * S_LEN + t) * D_IN_;
      float d = 0.f;
#pragma unroll
      for (int i = 0; i < D_IN_; ++i) d += win_[i] * xp[i];
      float a = fb + partial[tm * PSTR + j] + d + bj;
      float z = tanhf(a);
      float hn = (1.0f - LEAK_) * hprev[j] + LEAK_ * z;
      hnext[j] = hn;
      outB[(size_t)t * R_DIM + j] = hn;
    }
    __syncthreads();
    const int tn = t + 1;
    if ((tn & 3) == 0 && tn < S_LEN) {
      if (tm == BLK - 1) {
        const int s0 = tn;
        f32x4 acc[2][2];
#pragma unroll
        for (int mt = 0; mt < 2; ++mt)
#pragma unroll
          for (int nt = 0; nt < 2; ++nt) acc[mt][nt] = (f32x4){0.f, 0.f, 0.f, 0.f};
        const int taud[3] = {24, 96, 168};
#pragma unroll 1
        for (int ti = 0; ti < 3; ++ti) {
          const int tau = taud[ti];
          const float* W = Wfb + (size_t)(ti + 2) * R_DIM * R_DIM;
          const unsigned short* Wt = Wc + (size_t)(ti + 2) * R_DIM * R_DIM;
#pragma unroll 1
          for (int k0 = 0; k0 < R_DIM; k0 += 32) {
            bf16x8 afr[2], bfr[2];
#pragma unroll
            for (int mt = 0; mt < 2; ++mt) {
              int srow = mt * 16 + row16;
              int hs = s0 + srow - tau;
              bool v = (srow < BLK) && (hs >= 0);
              afr[mt] = load_afrag_g(outB + (size_t)(v ? hs : 0) * R_DIM, v, k0, kb);
            }
#pragma unroll
            for (int nt = 0; nt < 2; ++nt)
              bfr[nt] = load_bfrag(W, Wt, use_cache, k0, j0 + nt * 16 + row16, kb);
#pragma unroll
            for (int mt = 0; mt < 2; ++mt)
#pragma unroll
              for (int nt = 0; nt < 2; ++nt)
                acc[mt][nt] = __builtin_amdgcn_mfma_f32_16x16x32_bf16(afr[mt], bfr[nt], acc[mt][nt], 0, 0, 0);
          }
        }
#pragma unroll
        for (int mt = 0; mt < 2; ++mt)
#pragma unroll
          for (int q = 0; q < 4; ++q) {
            int srow = mt * 16 + kb * 4 + q;
            if (srow < BLK) {
#pragma unroll
              for (int nt = 0; nt < 2; ++nt)
                partial[srow * PSTR + j0 + nt * 16 + row16] = acc[mt][nt][q];
            }
          }
        __syncthreads();
      }
      {
        const int s0 = tn;
        const int sb = (tm == BLK - 1) ? 0 : tm + 1;
        const float* W = Wfb + (size_t)1 * R_DIM * R_DIM;
        const unsigned short* Wt = Wc + (size_t)1 * R_DIM * R_DIM;
        f32x4 acc[2];
        acc[0] = (f32x4){0.f, 0.f, 0.f, 0.f};
        acc[1] = (f32x4){0.f, 0.f, 0.f, 0.f};
#pragma unroll 1
        for (int k0 = 0; k0 < R_DIM; k0 += 32) {
          int srow = row16;
          int hs = s0 + srow - 4;
          bool v = (srow < 4);
          bf16x8 af = load_afrag_g(outB + (size_t)(v ? hs : 0) * R_DIM, v, k0, kb);
#pragma unroll
          for (int nt = 0; nt < 2; ++nt) {
            bf16x8 bf_ = load_bfrag(W, Wt, use_cache, k0, j0 + nt * 16 + row16, kb);
            acc[nt] = __builtin_amdgcn_mfma_f32_16x16x32_bf16(af, bf_, acc[nt], 0, 0, 0);
          }
        }
#pragma unroll
        for (int q = 0; q < 4; ++q) {
          int srow = kb * 4 + q;
          if (srow < 4) {
#pragma unroll
            for (int nt = 0; nt < 2; ++nt)
              partial[(sb + srow) * PSTR + j0 + nt * 16 + row16] += acc[nt][q];
          }
        }
        __syncthreads();
      }
    }
    float* tsw = hprev; hprev = hnext; hnext = tsw;
    tm = (tm == BLK - 1) ? 0 : tm + 1;
  }
}

extern "C" void kernel_launch(void* const* d_in, const int* in_sizes, int n_in,
                              void* d_out, int out_size, void* d_ws, size_t ws_size,
                              hipStream_t stream) {
  const float* x    = (const float*)d_in[0];
  const float* Win  = (const float*)d_in[1];
  const float* Wfb  = (const float*)d_in[2];
  const float* bias = (const float*)d_in[3];
  float* out = (float*)d_out;
  char* ws = (char*)d_ws;

  if (d_ws != nullptr && ws_size >= (size_t)WS_TOTAL) {
    unsigned short* Wc = (unsigned short*)(ws + WS_WC);
    unsigned* pool  = (unsigned*)(ws + WS_POOL);
    unsigned* wns   = (unsigned*)(ws + WS_WNS);
    unsigned* lists = (unsigned*)(ws + WS_LISTS);
    unsigned* cnt   = (unsigned*)(ws + WS_CNT);
    hipLaunchKernelGGL(prep_wc, dim3(5 * R_DIM), dim3(R_DIM), 0, stream, Wfb, Wc);
    hipLaunchKernelGGL(prep_lists, dim3(1), dim3(NTHR), 0, stream, Wfb, lists, cnt);
    hipLaunchKernelGGL(prep_sched, dim3(1), dim3(64), 0, stream, lists, cnt, pool, wns);
    hipFuncSetAttribute((const void*)reservoir_fast,
                        hipFuncAttributeMaxDynamicSharedMemorySize, F_LDS_BYTES);
    hipLaunchKernelGGL(reservoir_fast, dim3(N_BATCH), dim3(NTHR), F_LDS_BYTES, stream,
                       x, Win, Wfb, bias, out, (const unsigned short*)Wc,
                       (const unsigned*)pool, (const unsigned*)wns);
  } else {
    const size_t wc_bytes = (size_t)WS_WC_SZ;
    int use_cache = (d_ws != nullptr && ws_size >= wc_bytes) ? 1 : 0;
    unsigned short* Wc = use_cache ? (unsigned short*)d_ws : (unsigned short*)Wfb;
    if (use_cache)
      hipLaunchKernelGGL(prep_wc, dim3(5 * R_DIM), dim3(R_DIM), 0, stream, Wfb, Wc);
    hipFuncSetAttribute((const void*)reservoir_fb,
                        hipFuncAttributeMaxDynamicSharedMemorySize, LDS_BYTES_FB);
    hipLaunchKernelGGL(reservoir_fb, dim3(N_BATCH), dim3(NTHR), LDS_BYTES_FB, stream,
                       x, Win, Wfb, bias, out, (const unsigned short*)Wc, use_cache);
  }
}